// Round 13
// baseline (263.754 us; speedup 1.0000x reference)
//
#include <hip/hip_runtime.h>
#include <hip/hip_bf16.h>
#include <math.h>

// Problem constants (B=2, S=2048, D=1024, H=16, dk=64)
#define BATCH 2
#define SEQ   2048
#define DMODEL 1024
#define NHEAD 16
#define DK    64
#define M_TOT (BATCH*SEQ)      // 4096
#define KDIM  DMODEL           // 1024

typedef short bf16x8 __attribute__((ext_vector_type(8)));
typedef short bf16x4 __attribute__((ext_vector_type(4)));
typedef float f32x4  __attribute__((ext_vector_type(4)));
typedef __hip_bfloat16 bf16;

// 0.125 * log2(e) : folded into Q projection so softmax is exp2 directly
#define QSCALE 0.18033688011112042f

__device__ inline void gld_lds16(const void* g, void* l) {
    __builtin_amdgcn_global_load_lds(
        (const __attribute__((address_space(1))) unsigned int*)g,
        (__attribute__((address_space(3))) unsigned int*)l, 16, 0, 0);
}

__device__ inline unsigned pack2(float a, float b) {
    union { __hip_bfloat162 h; unsigned u; } t;
    t.h = __float22bfloat162_rn(make_float2(a, b));
    return t.u;
}

// ---- fused pre-pass, r13: grid-stride (2048 blocks, 8 iters) instead of
// 16384 one-shot 1KB blocks. y=0..2: q/k/v fp32->bf16 (4M elems each).
// y=3: the four 1M-elem weights packed into a 4M range.
__global__ __launch_bounds__(256) void conv_all(
    const float* __restrict__ q, const float* __restrict__ k, const float* __restrict__ v,
    const float* __restrict__ wq, const float* __restrict__ wk,
    const float* __restrict__ wv, const float* __restrict__ wo,
    bf16* __restrict__ qh, bf16* __restrict__ kh, bf16* __restrict__ vh,
    bf16* __restrict__ wqh, bf16* __restrict__ wkh, bf16* __restrict__ wvh,
    bf16* __restrict__ woh)
{
    const int y = blockIdx.y;
    const int NXE = M_TOT * DMODEL;          // 4M elems per y-slice
    for (int base = blockIdx.x * 1024 + threadIdx.x * 4; base < NXE;
         base += gridDim.x * 1024) {
        const int i = base;
        if (y < 3) {
            const float* src = y == 0 ? q : (y == 1 ? k : v);
            bf16* dst = y == 0 ? qh : (y == 1 ? kh : vh);
            float4 t = *(const float4*)(src + i);
            uint2 o;
            o.x = pack2(t.x, t.y);
            o.y = pack2(t.z, t.w);
            *(uint2*)(dst + i) = o;
        } else {
            const int w = i >> 20;               // 0..3 -> wq,wk,wv,wo
            const int j = i & ((1 << 20) - 1);
            const float* src = w == 0 ? wq : (w == 1 ? wk : (w == 2 ? wv : wo));
            bf16* dsth = w == 0 ? wqh : (w == 1 ? wkh : (w == 2 ? wvh : woh));
            float4 t = *(const float4*)(src + j);
            uint2 oh;
            oh.x = pack2(t.x, t.y);
            oh.y = pack2(t.z, t.w);
            *(uint2*)(dsth + j) = oh;
        }
    }
}

// ---- MFMA GEMM body: C[M,N] = A @ W^T (+ bias), bf16 [rows, 1024].
// 128x128 tile, BK=32, 4 waves (r8 proven form). Tile origin (row0,col0)
// passed in (callers apply XCD-aware swizzle).
// layout 0: f32 [M,1024] +bias; 1: bf16 [B,H,S,dk] (*scale); 2: bf16 [B,H,dk,S].
__device__ __forceinline__ void gemm_body(
    const bf16* __restrict__ Ah, const bf16* __restrict__ Wh,
    const float* __restrict__ bias, void* __restrict__ out,
    int layout, float scale, bf16* sA, bf16* sB, int kb, int ke,
    int row0, int col0)
{
    const int tid  = threadIdx.x;
    const int wave = tid >> 6, lane = tid & 63;
    const int ln   = lane & 15, quad = lane >> 4;
    const int wm   = wave >> 1, wn = wave & 1;

    const int srow = lane >> 2;
    const int clog = (lane & 3) ^ (srow & 3);
    const size_t gA0 = (size_t)(row0 + wave * 16 + srow) * KDIM + clog * 8;
    const size_t gB0 = (size_t)(col0 + wave * 16 + srow) * KDIM + clog * 8;
    const int ldsoff = (wave * 16 + srow) * 64 + (lane & 3) * 16;   // bytes

    const int swz = (quad ^ (ln & 3)) * 8;

    f32x4 acc[4][4] = {};

    for (int k0 = kb; k0 < ke; k0 += 32) {
        __syncthreads();
#pragma unroll
        for (int j = 0; j < 2; ++j) {
            const size_t go = (size_t)k0 + (size_t)j * 64 * KDIM;
            gld_lds16(Ah + gA0 + go, (char*)sA + j * 4096 + ldsoff);
            gld_lds16(Wh + gB0 + go, (char*)sB + j * 4096 + ldsoff);
        }
        __syncthreads();

        bf16x8 af[4], bfr[4];
#pragma unroll
        for (int t = 0; t < 4; ++t) {
            af[t]  = *(const bf16x8*)&sA[(wm * 64 + t * 16 + ln) * 32 + swz];
            bfr[t] = *(const bf16x8*)&sB[(wn * 64 + t * 16 + ln) * 32 + swz];
        }
#pragma unroll
        for (int mt = 0; mt < 4; ++mt)
#pragma unroll
            for (int nt = 0; nt < 4; ++nt)
                acc[mt][nt] = __builtin_amdgcn_mfma_f32_16x16x32_bf16(af[mt], bfr[nt], acc[mt][nt], 0, 0, 0);
    }

#pragma unroll
    for (int nt = 0; nt < 4; ++nt) {
        const int n = col0 + wn * 64 + nt * 16 + ln;
        const float bv = bias ? bias[n] : 0.f;
#pragma unroll
        for (int mt = 0; mt < 4; ++mt) {
            const int m0 = row0 + wm * 64 + mt * 16 + quad * 4;
            if (layout == 0) {
#pragma unroll
                for (int r = 0; r < 4; ++r)
                    ((float*)out)[(size_t)(m0 + r) * DMODEL + n] = (acc[mt][nt][r] + bv) * scale;
            } else if (layout == 1) {
                const int h = n >> 6, d = n & (DK - 1);
#pragma unroll
                for (int r = 0; r < 4; ++r) {
                    const int m = m0 + r;
                    const int b = m >> 11, s = m & (SEQ - 1);
                    ((bf16*)out)[((size_t)(b * NHEAD + h) * SEQ + s) * DK + d] =
                        __float2bfloat16((acc[mt][nt][r] + bv) * scale);
                }
            } else {
                // layout 2: 4 consecutive s -> one aligned 8B bf16x4 store
                const int h = n >> 6, d = n & (DK - 1);
                const int b = m0 >> 11, s0 = m0 & (SEQ - 1);
                union { bf16x4 v; uint2 u; } o4;
                o4.u.x = pack2((acc[mt][nt][0] + bv) * scale, (acc[mt][nt][1] + bv) * scale);
                o4.u.y = pack2((acc[mt][nt][2] + bv) * scale, (acc[mt][nt][3] + bv) * scale);
                *(bf16x4*)&((bf16*)out)[((size_t)(b * NHEAD + h) * DK + d) * SEQ + s0] = o4.v;
            }
        }
    }
}

struct QKVArgs {
    const bf16* A[3];
    const bf16* W[3];
    const float* bias[3];
    bf16* out[3];
    float scale[3];
    int layout[3];
};

// XCD-aware block swizzle (r11). 768 blocks = 8 xcd * (3 gemm * 4 mtile * 8 ntile).
// Each XCD owns a contiguous 4-Mtile band x all N of one GEMM:
// working set 1MB A-panel + 2MB W = 3MB <= 4MB per-XCD L2.
__global__ __launch_bounds__(256) void qkv_gemm(QKVArgs a) {
    __shared__ __align__(16) bf16 sA[128 * 32];
    __shared__ __align__(16) bf16 sB[128 * 32];
    const int lin = (blockIdx.z * gridDim.y + blockIdx.y) * gridDim.x + blockIdx.x;
    const int xcd = lin & 7;
    const int r   = lin >> 3;        // 0..95
    const int z   = r >> 5;          // GEMM 0..2
    const int t   = r & 31;
    const int mt  = xcd * 4 + (t >> 3);
    const int nt  = t & 7;
    gemm_body(a.A[z], a.W[z], a.bias[z],
              (void*)a.out[z], a.layout[z], a.scale[z], sA, sB, 0, KDIM,
              mt * 128, nt * 128);
}

// O projection in ONE pass (r12 proven): 128x64 tile, full K=1024,
// writes f32 out + bias directly. 512 blocks, acc[4][2], LDS 12KB.
__global__ __launch_bounds__(256) void gemm_o(
    const bf16* __restrict__ Ah, const bf16* __restrict__ Wh,
    const float* __restrict__ bias, float* __restrict__ out)
{
    __shared__ __align__(16) bf16 sA[128 * 32];
    __shared__ __align__(16) bf16 sB[64 * 32];

    const int tid  = threadIdx.x;
    const int wave = tid >> 6, lane = tid & 63;
    const int ln   = lane & 15, quad = lane >> 4;
    const int wm   = wave >> 1, wn = wave & 1;

    // XCD swizzle: 512 blocks = 8 xcd * 4 mtile * 16 ntile.
    const int lin  = blockIdx.y * gridDim.x + blockIdx.x;   // 0..511
    const int xcd  = lin & 7;
    const int r4   = lin >> 3;                              // 0..63
    const int row0 = (xcd * 4 + (r4 >> 4)) * 128;
    const int col0 = (r4 & 15) * 64;

    const int srow = lane >> 2;
    const int clog = (lane & 3) ^ (srow & 3);
    const size_t gA0 = (size_t)(row0 + wave * 16 + srow) * KDIM + clog * 8;
    const int ldsoffA = (wave * 16 + srow) * 64 + (lane & 3) * 16;

    const int brow  = tid >> 2;                              // 0..63
    const int bclog = (tid & 3) ^ (brow & 3);
    const size_t gB0 = (size_t)(col0 + brow) * KDIM + bclog * 8;
    const int ldsoffB = brow * 64 + (tid & 3) * 16;          // bytes = tid*16

    const int swz = (quad ^ (ln & 3)) * 8;

    f32x4 acc[4][2] = {};

    for (int k0 = 0; k0 < KDIM; k0 += 32) {
        __syncthreads();
#pragma unroll
        for (int j = 0; j < 2; ++j)
            gld_lds16(Ah + gA0 + k0 + (size_t)j * 64 * KDIM, (char*)sA + j * 4096 + ldsoffA);
        gld_lds16(Wh + gB0 + k0, (char*)sB + ldsoffB);
        __syncthreads();

        bf16x8 af[4], bfr[2];
#pragma unroll
        for (int t = 0; t < 4; ++t)
            af[t] = *(const bf16x8*)&sA[(wm * 64 + t * 16 + ln) * 32 + swz];
#pragma unroll
        for (int t = 0; t < 2; ++t)
            bfr[t] = *(const bf16x8*)&sB[(wn * 32 + t * 16 + ln) * 32 + swz];
#pragma unroll
        for (int mt = 0; mt < 4; ++mt)
#pragma unroll
            for (int nt = 0; nt < 2; ++nt)
                acc[mt][nt] = __builtin_amdgcn_mfma_f32_16x16x32_bf16(af[mt], bfr[nt], acc[mt][nt], 0, 0, 0);
    }

#pragma unroll
    for (int nt = 0; nt < 2; ++nt) {
        const int n = col0 + wn * 32 + nt * 16 + ln;
        const float bv = bias[n];
#pragma unroll
        for (int mt = 0; mt < 4; ++mt) {
            const int m0 = row0 + wm * 64 + mt * 16 + quad * 4;
#pragma unroll
            for (int r = 0; r < 4; ++r)
                out[(size_t)(m0 + r) * DMODEL + n] = acc[mt][nt][r] + bv;
        }
    }
}

// ---- MFMA flash attention: round-0 structure VERBATIM + XCD swizzle
// (r8-proven) + r13: s_setprio(1) around the two MFMA clusters (T5 —
// the only flash-edit family that never regressed: additive, no
// schedule/barrier change; m191 attn A/B +4-7%).
#define NKT (SEQ / 64)
__global__ __launch_bounds__(256) void flash_attn_mfma(
    const bf16* __restrict__ Q, const bf16* __restrict__ K,
    const bf16* __restrict__ Vt, bf16* __restrict__ ctxh)
{
    __shared__ __align__(16) bf16 Vts[64 * 64];

    const int tid  = threadIdx.x;
    const int wave = tid >> 6, lane = tid & 63;
    const int ln   = lane & 15, quad = lane >> 4;

    // XCD-aware swizzle (bijective on 512 blocks = 8 xcd * 4 heads * 16 qt)
    const int lin  = blockIdx.y * gridDim.x + blockIdx.x;   // 0..511
    const int slot = lin >> 3;                              // 0..63
    const int bh   = (lin & 7) * 4 + (slot >> 4);           // 4 heads per XCD
    const int qt   = slot & 15;                             // 128-row q tile
    const int b    = bh >> 4, h = bh & (NHEAD - 1);

    const int q0 = qt * 128 + wave * 32;
    const bf16* Qb = Q + ((size_t)bh * SEQ + q0) * DK;
    bf16x8 qf[2][2];
#pragma unroll
    for (int c = 0; c < 2; ++c)
#pragma unroll
        for (int nt = 0; nt < 2; ++nt)
            qf[c][nt] = *(const bf16x8*)(Qb + (size_t)(nt * 16 + ln) * DK + c * 32 + quad * 8);

    f32x4 of[2][4] = {};
    float lp[2] = {0.f, 0.f};

    const int sr  = tid >> 2;          // 0..63 (dk row of Vt)
    const int scb = (tid & 3) * 2;
    const int ssw = sr & 7;
    const bf16* Vg0 = Vt + ((size_t)bh * DK + sr) * SEQ;
    const bf16* Kl  = K + (size_t)bh * SEQ * DK + (size_t)ln * DK + quad * 8;

    // PV B-frag LDS addresses (kt-invariant, elements)
    int vaddr[4];
#pragma unroll
    for (int mt = 0; mt < 4; ++mt)
        vaddr[mt] = ln * 64 + (((2 * mt + (quad >> 1)) ^ (ln & 7)) * 8) + (quad & 1) * 4;

    bf16x8 kfA[2][4], kfB[2][4];
#pragma unroll
    for (int c = 0; c < 2; ++c)
#pragma unroll
        for (int mt = 0; mt < 4; ++mt)
            kfA[c][mt] = *(const bf16x8*)(Kl + (size_t)(mt * 16) * DK + c * 32);

    auto halfiter = [&](int ktc, bf16x8 (&kfc)[2][4], bf16x8 (&kfn)[2][4]) {
        __syncthreads();
        {
            const bf16* Vg = Vg0 + ktc * 64;
            uint4 v0 = *(const uint4*)(Vg + scb * 8);
            uint4 v1 = *(const uint4*)(Vg + scb * 8 + 8);
            *(uint4*)(&Vts[sr * 64 + ((scb    ) ^ ssw) * 8]) = v0;
            *(uint4*)(&Vts[sr * 64 + ((scb + 1) ^ ssw) * 8]) = v1;
        }
        __syncthreads();

        // prefetch next tile's K frags into the alternate register set
        const int ktn = (ktc + 1) & (NKT - 1);
#pragma unroll
        for (int c = 0; c < 2; ++c)
#pragma unroll
            for (int mt = 0; mt < 4; ++mt)
                kfn[c][mt] = *(const bf16x8*)(Kl + (size_t)(ktn * 64 + mt * 16) * DK + c * 32);

        // S^T[kv=64][q=32] = K @ Q^T  (x32 MFMA)
        f32x4 st[4][2] = {};
        __builtin_amdgcn_s_setprio(1);
#pragma unroll
        for (int c = 0; c < 2; ++c)
#pragma unroll
            for (int mt = 0; mt < 4; ++mt)
#pragma unroll
                for (int nt = 0; nt < 2; ++nt)
                    st[mt][nt] = __builtin_amdgcn_mfma_f32_16x16x32_bf16(kfc[c][mt], qf[c][nt], st[mt][nt], 0, 0, 0);
        __builtin_amdgcn_s_setprio(0);

        // P = exp2(S) -> x16 A-frags in registers; lp partials
        bf16x4 aP[4][2];
#pragma unroll
        for (int mt = 0; mt < 4; ++mt)
#pragma unroll
            for (int nt = 0; nt < 2; ++nt) {
                float p0 = __builtin_amdgcn_exp2f(st[mt][nt][0]);
                float p1 = __builtin_amdgcn_exp2f(st[mt][nt][1]);
                float p2 = __builtin_amdgcn_exp2f(st[mt][nt][2]);
                float p3 = __builtin_amdgcn_exp2f(st[mt][nt][3]);
                lp[nt] += (p0 + p1) + (p2 + p3);
                union { bf16x4 v; uint2 u; } uu;
                uu.u.x = pack2(p0, p1);
                uu.u.y = pack2(p2, p3);
                aP[mt][nt] = uu.v;
            }

        // O[q=32][dk=64] += P @ V  (x16 MFMA, A regs, B from LDS)
        __builtin_amdgcn_s_setprio(1);
#pragma unroll
        for (int mt = 0; mt < 4; ++mt)
#pragma unroll
            for (int nt = 0; nt < 4; ++nt) {
                bf16x4 vf = *(const bf16x4*)(&Vts[vaddr[mt] + nt * 1024]);
                of[0][nt] = __builtin_amdgcn_mfma_f32_16x16x16bf16_1k(aP[mt][0], vf, of[0][nt], 0, 0, 0);
                of[1][nt] = __builtin_amdgcn_mfma_f32_16x16x16bf16_1k(aP[mt][1], vf, of[1][nt], 0, 0, 0);
            }
        __builtin_amdgcn_s_setprio(0);
    };

    for (int kt = 0; kt < NKT; kt += 2) {
        halfiter(kt,     kfA, kfB);
        halfiter(kt + 1, kfB, kfA);
    }

    // row-sum reduce over quads; then fetch per-O-row inverse
#pragma unroll
    for (int nt = 0; nt < 2; ++nt) {
        lp[nt] += __shfl_xor(lp[nt], 16, 64);
        lp[nt] += __shfl_xor(lp[nt], 32, 64);
    }
    float linv[2][4];
#pragma unroll
    for (int mtP = 0; mtP < 2; ++mtP)
#pragma unroll
        for (int r = 0; r < 4; ++r)
            linv[mtP][r] = 1.0f / __shfl(lp[mtP], quad * 4 + r, 64);

    const size_t base = ((size_t)b * SEQ + q0) * DMODEL + h * DK;
#pragma unroll
    for (int mtP = 0; mtP < 2; ++mtP)
#pragma unroll
        for (int nt = 0; nt < 4; ++nt)
#pragma unroll
            for (int r = 0; r < 4; ++r) {
                const float v = of[mtP][nt][r] * linv[mtP][r];
                const size_t idx = base + (size_t)(mtP * 16 + quad * 4 + r) * DMODEL + nt * 16 + ln;
                ctxh[idx] = __float2bfloat16(v);
            }
}

extern "C" void kernel_launch(void* const* d_in, const int* in_sizes, int n_in,
                              void* d_out, int out_size, void* d_ws, size_t ws_size,
                              hipStream_t stream) {
    const float* q  = (const float*)d_in[0];
    const float* k  = (const float*)d_in[1];
    const float* v  = (const float*)d_in[2];
    const float* wq = (const float*)d_in[3];
    const float* bq = (const float*)d_in[4];
    const float* wk = (const float*)d_in[5];
    const float* bk = (const float*)d_in[6];
    const float* wv = (const float*)d_in[7];
    const float* bv = (const float*)d_in[8];
    const float* wo = (const float*)d_in[9];
    const float* bo = (const float*)d_in[10];
    float* out = (float*)d_out;

    char* ws = (char*)d_ws;
    const size_t MB = 1u << 20;
    bf16* wq_hi = (bf16*)(ws + 0 * MB);    // 2 MB each
    bf16* wk_hi = (bf16*)(ws + 2 * MB);
    bf16* wv_hi = (bf16*)(ws + 4 * MB);
    bf16* wo_hi = (bf16*)(ws + 6 * MB);
    bf16* q_hi  = (bf16*)(ws + 8 * MB);    // 8 MB each; dead after qkv_gemm
    bf16* k_hi  = (bf16*)(ws + 16 * MB);
    bf16* v_hi  = (bf16*)(ws + 24 * MB);
    bf16* Qp    = (bf16*)(ws + 32 * MB);   // dead after flash
    bf16* Kp    = (bf16*)(ws + 40 * MB);
    bf16* Vpt   = (bf16*)(ws + 48 * MB);
    bf16* ctx_h = (bf16*)(ws + 8 * MB);    // overlays dead q_hi

    conv_all<<<dim3(512, 4), 256, 0, stream>>>(
        q, k, v, wq, wk, wv, wo,
        q_hi, k_hi, v_hi, wq_hi, wk_hi, wv_hi, wo_hi);

    QKVArgs qa;
    qa.A[0] = q_hi;  qa.A[1] = k_hi;  qa.A[2] = v_hi;
    qa.W[0] = wq_hi; qa.W[1] = wk_hi; qa.W[2] = wv_hi;
    qa.bias[0] = bq; qa.bias[1] = bk; qa.bias[2] = bv;
    qa.out[0] = Qp;  qa.out[1] = Kp;  qa.out[2] = Vpt;
    qa.scale[0] = QSCALE; qa.scale[1] = 1.0f; qa.scale[2] = 1.0f;
    qa.layout[0] = 1; qa.layout[1] = 1; qa.layout[2] = 2;

    dim3 qgrid(DMODEL / 128, M_TOT / 128, 3);   // (8, 32, 3) - swizzled in-kernel
    qkv_gemm<<<qgrid, 256, 0, stream>>>(qa);

    dim3 fgrid(SEQ / 128, BATCH * NHEAD);       // (16, 32) = 512 blocks
    flash_attn_mfma<<<fgrid, 256, 0, stream>>>(Qp, Kp, Vpt, ctx_h);

    dim3 ogrid(16, 32);                         // 512 blocks, 128x64 tiles
    gemm_o<<<ogrid, 256, 0, stream>>>(ctx_h, wo_hi, bo, out);
}

// Round 14
// 256.205 us; speedup vs baseline: 1.0295x; 1.0295x over previous
//
#include <hip/hip_runtime.h>
#include <hip/hip_bf16.h>
#include <math.h>

// Problem constants (B=2, S=2048, D=1024, H=16, dk=64)
#define BATCH 2
#define SEQ   2048
#define DMODEL 1024
#define NHEAD 16
#define DK    64
#define M_TOT (BATCH*SEQ)      // 4096
#define KDIM  DMODEL           // 1024

typedef short bf16x8 __attribute__((ext_vector_type(8)));
typedef short bf16x4 __attribute__((ext_vector_type(4)));
typedef float f32x4  __attribute__((ext_vector_type(4)));
typedef __hip_bfloat16 bf16;

// 0.125 * log2(e) : folded into Q projection so softmax is exp2 directly
#define QSCALE 0.18033688011112042f

__device__ inline void gld_lds16(const void* g, void* l) {
    __builtin_amdgcn_global_load_lds(
        (const __attribute__((address_space(1))) unsigned int*)g,
        (__attribute__((address_space(3))) unsigned int*)l, 16, 0, 0);
}

__device__ inline unsigned pack2(float a, float b) {
    union { __hip_bfloat162 h; unsigned u; } t;
    t.h = __float22bfloat162_rn(make_float2(a, b));
    return t.u;
}

// ---- fused pre-pass. y=0..2: q/k/v fp32->bf16 (4M elems each).
// y=3: the four 1M-elem weights packed into a 4M range (all hi-only now).
__global__ __launch_bounds__(256) void conv_all(
    const float* __restrict__ q, const float* __restrict__ k, const float* __restrict__ v,
    const float* __restrict__ wq, const float* __restrict__ wk,
    const float* __restrict__ wv, const float* __restrict__ wo,
    bf16* __restrict__ qh, bf16* __restrict__ kh, bf16* __restrict__ vh,
    bf16* __restrict__ wqh, bf16* __restrict__ wkh, bf16* __restrict__ wvh,
    bf16* __restrict__ woh)
{
    const int y = blockIdx.y;
    const int i = (blockIdx.x * 256 + threadIdx.x) * 4;
    if (y < 3) {
        const float* src = y == 0 ? q : (y == 1 ? k : v);
        bf16* dst = y == 0 ? qh : (y == 1 ? kh : vh);
        float4 t = *(const float4*)(src + i);
        uint2 o;
        o.x = pack2(t.x, t.y);
        o.y = pack2(t.z, t.w);
        *(uint2*)(dst + i) = o;
    } else {
        const int w = i >> 20;               // 0..3 -> wq,wk,wv,wo
        const int j = i & ((1 << 20) - 1);
        const float* src = w == 0 ? wq : (w == 1 ? wk : (w == 2 ? wv : wo));
        bf16* dsth = w == 0 ? wqh : (w == 1 ? wkh : (w == 2 ? wvh : woh));
        float4 t = *(const float4*)(src + j);
        uint2 oh;
        oh.x = pack2(t.x, t.y);
        oh.y = pack2(t.z, t.w);
        *(uint2*)(dsth + j) = oh;
    }
}

// ---- MFMA GEMM body: C[M,N] = A @ W^T (+ bias), bf16 [rows, 1024].
// 128x128 tile, BK=32, 4 waves (r8 proven form). Tile origin (row0,col0)
// passed in (callers apply XCD-aware swizzle).
// layout 0: f32 [M,1024] +bias; 1: bf16 [B,H,S,dk] (*scale); 2: bf16 [B,H,dk,S].
__device__ __forceinline__ void gemm_body(
    const bf16* __restrict__ Ah, const bf16* __restrict__ Wh,
    const float* __restrict__ bias, void* __restrict__ out,
    int layout, float scale, bf16* sA, bf16* sB, int kb, int ke,
    int row0, int col0)
{
    const int tid  = threadIdx.x;
    const int wave = tid >> 6, lane = tid & 63;
    const int ln   = lane & 15, quad = lane >> 4;
    const int wm   = wave >> 1, wn = wave & 1;

    const int srow = lane >> 2;
    const int clog = (lane & 3) ^ (srow & 3);
    const size_t gA0 = (size_t)(row0 + wave * 16 + srow) * KDIM + clog * 8;
    const size_t gB0 = (size_t)(col0 + wave * 16 + srow) * KDIM + clog * 8;
    const int ldsoff = (wave * 16 + srow) * 64 + (lane & 3) * 16;   // bytes

    const int swz = (quad ^ (ln & 3)) * 8;

    f32x4 acc[4][4] = {};

    for (int k0 = kb; k0 < ke; k0 += 32) {
        __syncthreads();
#pragma unroll
        for (int j = 0; j < 2; ++j) {
            const size_t go = (size_t)k0 + (size_t)j * 64 * KDIM;
            gld_lds16(Ah + gA0 + go, (char*)sA + j * 4096 + ldsoff);
            gld_lds16(Wh + gB0 + go, (char*)sB + j * 4096 + ldsoff);
        }
        __syncthreads();

        bf16x8 af[4], bfr[4];
#pragma unroll
        for (int t = 0; t < 4; ++t) {
            af[t]  = *(const bf16x8*)&sA[(wm * 64 + t * 16 + ln) * 32 + swz];
            bfr[t] = *(const bf16x8*)&sB[(wn * 64 + t * 16 + ln) * 32 + swz];
        }
#pragma unroll
        for (int mt = 0; mt < 4; ++mt)
#pragma unroll
            for (int nt = 0; nt < 4; ++nt)
                acc[mt][nt] = __builtin_amdgcn_mfma_f32_16x16x32_bf16(af[mt], bfr[nt], acc[mt][nt], 0, 0, 0);
    }

#pragma unroll
    for (int nt = 0; nt < 4; ++nt) {
        const int n = col0 + wn * 64 + nt * 16 + ln;
        const float bv = bias ? bias[n] : 0.f;
#pragma unroll
        for (int mt = 0; mt < 4; ++mt) {
            const int m0 = row0 + wm * 64 + mt * 16 + quad * 4;
            if (layout == 0) {
#pragma unroll
                for (int r = 0; r < 4; ++r)
                    ((float*)out)[(size_t)(m0 + r) * DMODEL + n] = (acc[mt][nt][r] + bv) * scale;
            } else if (layout == 1) {
                const int h = n >> 6, d = n & (DK - 1);
#pragma unroll
                for (int r = 0; r < 4; ++r) {
                    const int m = m0 + r;
                    const int b = m >> 11, s = m & (SEQ - 1);
                    ((bf16*)out)[((size_t)(b * NHEAD + h) * SEQ + s) * DK + d] =
                        __float2bfloat16((acc[mt][nt][r] + bv) * scale);
                }
            } else {
                // layout 2: 4 consecutive s -> one aligned 8B bf16x4 store
                const int h = n >> 6, d = n & (DK - 1);
                const int b = m0 >> 11, s0 = m0 & (SEQ - 1);
                union { bf16x4 v; uint2 u; } o4;
                o4.u.x = pack2((acc[mt][nt][0] + bv) * scale, (acc[mt][nt][1] + bv) * scale);
                o4.u.y = pack2((acc[mt][nt][2] + bv) * scale, (acc[mt][nt][3] + bv) * scale);
                *(bf16x4*)&((bf16*)out)[((size_t)(b * NHEAD + h) * DK + d) * SEQ + s0] = o4.v;
            }
        }
    }
}

struct QKVArgs {
    const bf16* A[3];
    const bf16* W[3];
    const float* bias[3];
    bf16* out[3];
    float scale[3];
    int layout[3];
};

// XCD-aware block swizzle (r11). 768 blocks = 8 xcd * (3 gemm * 4 mtile * 8 ntile).
// Each XCD owns a contiguous 4-Mtile band x all N of one GEMM:
// working set 1MB A-panel + 2MB W = 3MB <= 4MB per-XCD L2.
__global__ __launch_bounds__(256) void qkv_gemm(QKVArgs a) {
    __shared__ __align__(16) bf16 sA[128 * 32];
    __shared__ __align__(16) bf16 sB[128 * 32];
    const int lin = (blockIdx.z * gridDim.y + blockIdx.y) * gridDim.x + blockIdx.x;
    const int xcd = lin & 7;
    const int r   = lin >> 3;        // 0..95
    const int z   = r >> 5;          // GEMM 0..2
    const int t   = r & 31;
    const int mt  = xcd * 4 + (t >> 3);
    const int nt  = t & 7;
    gemm_body(a.A[z], a.W[z], a.bias[z],
              (void*)a.out[z], a.layout[z], a.scale[z], sA, sB, 0, KDIM,
              mt * 128, nt * 128);
}

// O projection in ONE pass (r12 proven): 128x64 tile, full K=1024,
// writes f32 out + bias directly. 512 blocks, acc[4][2], LDS 12KB.
__global__ __launch_bounds__(256) void gemm_o(
    const bf16* __restrict__ Ah, const bf16* __restrict__ Wh,
    const float* __restrict__ bias, float* __restrict__ out)
{
    __shared__ __align__(16) bf16 sA[128 * 32];
    __shared__ __align__(16) bf16 sB[64 * 32];

    const int tid  = threadIdx.x;
    const int wave = tid >> 6, lane = tid & 63;
    const int ln   = lane & 15, quad = lane >> 4;
    const int wm   = wave >> 1, wn = wave & 1;

    // XCD swizzle: 512 blocks = 8 xcd * 4 mtile * 16 ntile.
    const int lin  = blockIdx.y * gridDim.x + blockIdx.x;   // 0..511
    const int xcd  = lin & 7;
    const int r4   = lin >> 3;                              // 0..63
    const int row0 = (xcd * 4 + (r4 >> 4)) * 128;
    const int col0 = (r4 & 15) * 64;

    const int srow = lane >> 2;
    const int clog = (lane & 3) ^ (srow & 3);
    const size_t gA0 = (size_t)(row0 + wave * 16 + srow) * KDIM + clog * 8;
    const int ldsoffA = (wave * 16 + srow) * 64 + (lane & 3) * 16;

    const int brow  = tid >> 2;                              // 0..63
    const int bclog = (tid & 3) ^ (brow & 3);
    const size_t gB0 = (size_t)(col0 + brow) * KDIM + bclog * 8;
    const int ldsoffB = brow * 64 + (tid & 3) * 16;          // bytes = tid*16

    const int swz = (quad ^ (ln & 3)) * 8;

    f32x4 acc[4][2] = {};

    for (int k0 = 0; k0 < KDIM; k0 += 32) {
        __syncthreads();
#pragma unroll
        for (int j = 0; j < 2; ++j)
            gld_lds16(Ah + gA0 + k0 + (size_t)j * 64 * KDIM, (char*)sA + j * 4096 + ldsoffA);
        gld_lds16(Wh + gB0 + k0, (char*)sB + ldsoffB);
        __syncthreads();

        bf16x8 af[4], bfr[2];
#pragma unroll
        for (int t = 0; t < 4; ++t)
            af[t] = *(const bf16x8*)&sA[(wm * 64 + t * 16 + ln) * 32 + swz];
#pragma unroll
        for (int t = 0; t < 2; ++t)
            bfr[t] = *(const bf16x8*)&sB[(wn * 32 + t * 16 + ln) * 32 + swz];
#pragma unroll
        for (int mt = 0; mt < 4; ++mt)
#pragma unroll
            for (int nt = 0; nt < 2; ++nt)
                acc[mt][nt] = __builtin_amdgcn_mfma_f32_16x16x32_bf16(af[mt], bfr[nt], acc[mt][nt], 0, 0, 0);
    }

#pragma unroll
    for (int nt = 0; nt < 2; ++nt) {
        const int n = col0 + wn * 32 + nt * 16 + ln;
        const float bv = bias[n];
#pragma unroll
        for (int mt = 0; mt < 4; ++mt) {
            const int m0 = row0 + wm * 64 + mt * 16 + quad * 4;
#pragma unroll
            for (int r = 0; r < 4; ++r)
                out[(size_t)(m0 + r) * DMODEL + n] = acc[mt][nt][r] + bv;
        }
    }
}

// ---- MFMA flash attention: round-0 structure VERBATIM + XCD swizzle
// (r8-proven: FETCH 70->12MB; r13's setprio reverted — it inflated VGPR
// 88->128 and cost 2us).
#define NKT (SEQ / 64)
__global__ __launch_bounds__(256) void flash_attn_mfma(
    const bf16* __restrict__ Q, const bf16* __restrict__ K,
    const bf16* __restrict__ Vt, bf16* __restrict__ ctxh)
{
    __shared__ __align__(16) bf16 Vts[64 * 64];

    const int tid  = threadIdx.x;
    const int wave = tid >> 6, lane = tid & 63;
    const int ln   = lane & 15, quad = lane >> 4;

    // XCD-aware swizzle (bijective on 512 blocks = 8 xcd * 4 heads * 16 qt):
    // all 16 q-tiles of one head share one XCD (per-head KV 512KB << 4MB L2).
    const int lin  = blockIdx.y * gridDim.x + blockIdx.x;   // 0..511
    const int slot = lin >> 3;                              // 0..63
    const int bh   = (lin & 7) * 4 + (slot >> 4);           // 4 heads per XCD
    const int qt   = slot & 15;                             // 128-row q tile
    const int b    = bh >> 4, h = bh & (NHEAD - 1);

    const int q0 = qt * 128 + wave * 32;
    const bf16* Qb = Q + ((size_t)bh * SEQ + q0) * DK;
    bf16x8 qf[2][2];
#pragma unroll
    for (int c = 0; c < 2; ++c)
#pragma unroll
        for (int nt = 0; nt < 2; ++nt)
            qf[c][nt] = *(const bf16x8*)(Qb + (size_t)(nt * 16 + ln) * DK + c * 32 + quad * 8);

    f32x4 of[2][4] = {};
    float lp[2] = {0.f, 0.f};

    const int sr  = tid >> 2;          // 0..63 (dk row of Vt)
    const int scb = (tid & 3) * 2;
    const int ssw = sr & 7;
    const bf16* Vg0 = Vt + ((size_t)bh * DK + sr) * SEQ;
    const bf16* Kl  = K + (size_t)bh * SEQ * DK + (size_t)ln * DK + quad * 8;

    // PV B-frag LDS addresses (kt-invariant, elements)
    int vaddr[4];
#pragma unroll
    for (int mt = 0; mt < 4; ++mt)
        vaddr[mt] = ln * 64 + (((2 * mt + (quad >> 1)) ^ (ln & 7)) * 8) + (quad & 1) * 4;

    bf16x8 kfA[2][4], kfB[2][4];
#pragma unroll
    for (int c = 0; c < 2; ++c)
#pragma unroll
        for (int mt = 0; mt < 4; ++mt)
            kfA[c][mt] = *(const bf16x8*)(Kl + (size_t)(mt * 16) * DK + c * 32);

    auto halfiter = [&](int ktc, bf16x8 (&kfc)[2][4], bf16x8 (&kfn)[2][4]) {
        __syncthreads();
        {
            const bf16* Vg = Vg0 + ktc * 64;
            uint4 v0 = *(const uint4*)(Vg + scb * 8);
            uint4 v1 = *(const uint4*)(Vg + scb * 8 + 8);
            *(uint4*)(&Vts[sr * 64 + ((scb    ) ^ ssw) * 8]) = v0;
            *(uint4*)(&Vts[sr * 64 + ((scb + 1) ^ ssw) * 8]) = v1;
        }
        __syncthreads();

        // prefetch next tile's K frags into the alternate register set
        const int ktn = (ktc + 1) & (NKT - 1);
#pragma unroll
        for (int c = 0; c < 2; ++c)
#pragma unroll
            for (int mt = 0; mt < 4; ++mt)
                kfn[c][mt] = *(const bf16x8*)(Kl + (size_t)(ktn * 64 + mt * 16) * DK + c * 32);

        // S^T[kv=64][q=32] = K @ Q^T  (x32 MFMA)
        f32x4 st[4][2] = {};
#pragma unroll
        for (int c = 0; c < 2; ++c)
#pragma unroll
            for (int mt = 0; mt < 4; ++mt)
#pragma unroll
                for (int nt = 0; nt < 2; ++nt)
                    st[mt][nt] = __builtin_amdgcn_mfma_f32_16x16x32_bf16(kfc[c][mt], qf[c][nt], st[mt][nt], 0, 0, 0);

        // P = exp2(S) -> x16 A-frags in registers; lp partials
        bf16x4 aP[4][2];
#pragma unroll
        for (int mt = 0; mt < 4; ++mt)
#pragma unroll
            for (int nt = 0; nt < 2; ++nt) {
                float p0 = __builtin_amdgcn_exp2f(st[mt][nt][0]);
                float p1 = __builtin_amdgcn_exp2f(st[mt][nt][1]);
                float p2 = __builtin_amdgcn_exp2f(st[mt][nt][2]);
                float p3 = __builtin_amdgcn_exp2f(st[mt][nt][3]);
                lp[nt] += (p0 + p1) + (p2 + p3);
                union { bf16x4 v; uint2 u; } uu;
                uu.u.x = pack2(p0, p1);
                uu.u.y = pack2(p2, p3);
                aP[mt][nt] = uu.v;
            }

        // O[q=32][dk=64] += P @ V  (x16 MFMA, A regs, B from LDS)
#pragma unroll
        for (int mt = 0; mt < 4; ++mt)
#pragma unroll
            for (int nt = 0; nt < 4; ++nt) {
                bf16x4 vf = *(const bf16x4*)(&Vts[vaddr[mt] + nt * 1024]);
                of[0][nt] = __builtin_amdgcn_mfma_f32_16x16x16bf16_1k(aP[mt][0], vf, of[0][nt], 0, 0, 0);
                of[1][nt] = __builtin_amdgcn_mfma_f32_16x16x16bf16_1k(aP[mt][1], vf, of[1][nt], 0, 0, 0);
            }
    };

    for (int kt = 0; kt < NKT; kt += 2) {
        halfiter(kt,     kfA, kfB);
        halfiter(kt + 1, kfB, kfA);
    }

    // row-sum reduce over quads; then fetch per-O-row inverse
#pragma unroll
    for (int nt = 0; nt < 2; ++nt) {
        lp[nt] += __shfl_xor(lp[nt], 16, 64);
        lp[nt] += __shfl_xor(lp[nt], 32, 64);
    }
    float linv[2][4];
#pragma unroll
    for (int mtP = 0; mtP < 2; ++mtP)
#pragma unroll
        for (int r = 0; r < 4; ++r)
            linv[mtP][r] = 1.0f / __shfl(lp[mtP], quad * 4 + r, 64);

    const size_t base = ((size_t)b * SEQ + q0) * DMODEL + h * DK;
#pragma unroll
    for (int mtP = 0; mtP < 2; ++mtP)
#pragma unroll
        for (int nt = 0; nt < 4; ++nt)
#pragma unroll
            for (int r = 0; r < 4; ++r) {
                const float v = of[mtP][nt][r] * linv[mtP][r];
                const size_t idx = base + (size_t)(mtP * 16 + quad * 4 + r) * DMODEL + nt * 16 + ln;
                ctxh[idx] = __float2bfloat16(v);
            }
}

extern "C" void kernel_launch(void* const* d_in, const int* in_sizes, int n_in,
                              void* d_out, int out_size, void* d_ws, size_t ws_size,
                              hipStream_t stream) {
    const float* q  = (const float*)d_in[0];
    const float* k  = (const float*)d_in[1];
    const float* v  = (const float*)d_in[2];
    const float* wq = (const float*)d_in[3];
    const float* bq = (const float*)d_in[4];
    const float* wk = (const float*)d_in[5];
    const float* bk = (const float*)d_in[6];
    const float* wv = (const float*)d_in[7];
    const float* bv = (const float*)d_in[8];
    const float* wo = (const float*)d_in[9];
    const float* bo = (const float*)d_in[10];
    float* out = (float*)d_out;

    char* ws = (char*)d_ws;
    const size_t MB = 1u << 20;
    bf16* wq_hi = (bf16*)(ws + 0 * MB);    // 2 MB each
    bf16* wk_hi = (bf16*)(ws + 2 * MB);
    bf16* wv_hi = (bf16*)(ws + 4 * MB);
    bf16* wo_hi = (bf16*)(ws + 6 * MB);
    bf16* q_hi  = (bf16*)(ws + 8 * MB);    // 8 MB each; dead after qkv_gemm
    bf16* k_hi  = (bf16*)(ws + 16 * MB);
    bf16* v_hi  = (bf16*)(ws + 24 * MB);
    bf16* Qp    = (bf16*)(ws + 32 * MB);   // dead after flash
    bf16* Kp    = (bf16*)(ws + 40 * MB);
    bf16* Vpt   = (bf16*)(ws + 48 * MB);
    bf16* ctx_h = (bf16*)(ws + 8 * MB);    // overlays dead q_hi

    const int NX = M_TOT * DMODEL;   // 4M

    conv_all<<<dim3(NX / 1024, 4), 256, 0, stream>>>(
        q, k, v, wq, wk, wv, wo,
        q_hi, k_hi, v_hi, wq_hi, wk_hi, wv_hi, wo_hi);

    QKVArgs qa;
    qa.A[0] = q_hi;  qa.A[1] = k_hi;  qa.A[2] = v_hi;
    qa.W[0] = wq_hi; qa.W[1] = wk_hi; qa.W[2] = wv_hi;
    qa.bias[0] = bq; qa.bias[1] = bk; qa.bias[2] = bv;
    qa.out[0] = Qp;  qa.out[1] = Kp;  qa.out[2] = Vpt;
    qa.scale[0] = QSCALE; qa.scale[1] = 1.0f; qa.scale[2] = 1.0f;
    qa.layout[0] = 1; qa.layout[1] = 1; qa.layout[2] = 2;

    dim3 qgrid(DMODEL / 128, M_TOT / 128, 3);   // (8, 32, 3) - swizzled in-kernel
    qkv_gemm<<<qgrid, 256, 0, stream>>>(qa);

    dim3 fgrid(SEQ / 128, BATCH * NHEAD);       // (16, 32) = 512 blocks
    flash_attn_mfma<<<fgrid, 256, 0, stream>>>(Qp, Kp, Vpt, ctx_h);

    dim3 ogrid(16, 32);                         // 512 blocks, 128x64 tiles
    gemm_o<<<ogrid, 256, 0, stream>>>(ctx_h, wo_hi, bo, out);
}